// Round 4
// baseline (292.634 us; speedup 1.0000x reference)
//
#include <hip/hip_runtime.h>
#include <stdint.h>

#define M_DIM 4096
#define N_DIM 4096
#define K_DIM 4096

#define BM 256
#define BN 256
#define BK 32
#define NT (K_DIM / BK)   // 128 K-tiles

typedef __bf16 bf16x8 __attribute__((ext_vector_type(8)));
typedef float f32x4 __attribute__((ext_vector_type(4)));
typedef unsigned short us8 __attribute__((ext_vector_type(8)));
typedef unsigned short us4v __attribute__((ext_vector_type(4)));

// round-to-nearest-even fp32 -> bf16 bits
__device__ __forceinline__ unsigned short f2bf(float f) {
    unsigned u = __builtin_bit_cast(unsigned, f);
    u = (u + 0x7FFFu + ((u >> 16) & 1u)) >> 16;
    return (unsigned short)u;
}

// ---------------------------------------------------------------- prep_a (UNCHANGED)
__global__ __launch_bounds__(256) void prep_a(const float* __restrict__ A,
                                              unsigned short* __restrict__ Abf) {
#pragma unroll
    for (int it = 0; it < 4; ++it) {
        const int i = blockIdx.x * 1024 + it * 256 + threadIdx.x;  // us8 index
        const float4 v0 = ((const float4*)A)[2 * i];
        const float4 v1 = ((const float4*)A)[2 * i + 1];
        us8 o;
        o[0] = f2bf(v0.x); o[1] = f2bf(v0.y); o[2] = f2bf(v0.z); o[3] = f2bf(v0.w);
        o[4] = f2bf(v1.x); o[5] = f2bf(v1.y); o[6] = f2bf(v1.z); o[7] = f2bf(v1.w);
        ((us8*)Abf)[i] = o;
    }
}

// ---------------------------------------------------------------- prep_w (UNCHANGED)
__global__ __launch_bounds__(256) void prep_w(const float* __restrict__ W,
                                              unsigned short* __restrict__ Wt) {
    __shared__ __align__(16) unsigned short Lt[128 * 68];
    const int t = threadIdx.x;
    const int k0 = (blockIdx.x >> 6) * 128;
    const int n0 = (blockIdx.x & 63) * 64;

#pragma unroll
    for (int q = 0; q < 8; ++q) {
        const int idx = q * 256 + t;
        const int k = idx >> 4;
        const int a = idx & 15;
        const float4 v = *(const float4*)(W + (size_t)(k0 + k) * N_DIM + n0 + 4 * a);
        const int ap = a ^ ((k ^ (k >> 3)) & 7);
        us4v o;
        o[0] = f2bf(v.x); o[1] = f2bf(v.y); o[2] = f2bf(v.z); o[3] = f2bf(v.w);
        *(us4v*)(Lt + k * 68 + 4 * ap) = o;
    }
    __syncthreads();

#pragma unroll
    for (int q = 0; q < 4; ++q) {
        const int s = q * 256 + t;
        const int n = s >> 4;
        const int c = s & 15;
        us8 o;
#pragma unroll
        for (int j = 0; j < 8; ++j) {
            const int k = 8 * c + j;
            const int ap = (n >> 2) ^ ((k ^ (k >> 3)) & 7);
            o[j] = Lt[k * 68 + 4 * ap + (n & 3)];
        }
        *(us8*)(Wt + (size_t)(n0 + n) * K_DIM + k0 + 8 * c) = o;
    }
}

// ---------------------------------------------------------------- GEMM
// 256x256 tile, BK=32, 512 threads (8 waves, 2M x 4N), per-wave 128x64 out.
// Triple-buffered LDS (96 KB), counted vmcnt(4), raw s_barrier.
// R3/R4: per-tile 2-phase schedule (m201-style): each phase =
// {ds_read frags; issue stage; BAR; lgkmcnt(0); setprio1; 16 MFMA; setprio0;
//  BAR}. End-of-phase barrier sits AFTER each wave's lgkmcnt(0), so no
// in-flight ds_read can observe a later global_load_lds write (buffer-reuse
// safety), and waves stay phase-aligned so ds_read bursts interleave with
// other waves' MFMA clusters instead of piling up.
__device__ __forceinline__ void load_lds16(const void* g, void* l) {
    __builtin_amdgcn_global_load_lds(
        (const __attribute__((address_space(1))) void*)g,
        (__attribute__((address_space(3))) void*)l,
        16, 0, 0);
}

__global__ __launch_bounds__(512, 2) void gemm_bf16(const unsigned short* __restrict__ A,
                                                    const unsigned short* __restrict__ Bt,
                                                    const float* __restrict__ bias,
                                                    float* __restrict__ C) {
    __shared__ __align__(16) unsigned short As[3][BM * BK];  // 3 x 16 KB
    __shared__ __align__(16) unsigned short Bs[3][BN * BK];  // 3 x 16 KB

    // XCD-aware swizzle: 256 blocks, 8 XCDs, 32 consecutive tiles per XCD
    const int bid = blockIdx.x;
    const int g = (bid & 7) * 32 + (bid >> 3);
    const int m0 = (g >> 4) * BM;
    const int n0 = (g & 15) * BN;

    const int tid = threadIdx.x;
    const int lane = tid & 63;
    const int wave = tid >> 6;            // 0..7
    const int wm = (wave >> 2) * 128;     // 2 M-halves of 128
    const int wn = (wave & 3) * 64;       // 4 N-quarters of 64
    const int lrow = lane & 15;
    const int quad = lane >> 4;
    const int kofs = (quad ^ ((lrow >> 1) & 3)) * 8;

    // staging: thread t fills 16B slots t and 512+t of each buffer.
    const int r0 = tid >> 2;                          // 0..127
    const int c0 = (tid & 3) ^ ((tid >> 3) & 3);
    const unsigned short* agp0 = A + (size_t)(m0 + r0) * K_DIM + c0 * 8;
    const unsigned short* agp1 = agp0 + (size_t)128 * K_DIM;
    const unsigned short* bgp0 = Bt + (size_t)(n0 + r0) * K_DIM + c0 * 8;
    const unsigned short* bgp1 = bgp0 + (size_t)128 * K_DIM;

    const int abase = (wm + lrow) * BK + kofs;
    const int bbase = (wn + lrow) * BK + kofs;

    f32x4 acc[2][4][4] = {};

#define STAGE_A(bi, t) do {                                   \
        load_lds16(agp0 + (size_t)(t) * BK, &As[bi][tid * 8]);        \
        load_lds16(agp1 + (size_t)(t) * BK, &As[bi][4096 + tid * 8]); \
    } while (0)
#define STAGE_B(bi, t) do {                                   \
        load_lds16(bgp0 + (size_t)(t) * BK, &Bs[bi][tid * 8]);        \
        load_lds16(bgp1 + (size_t)(t) * BK, &Bs[bi][4096 + tid * 8]); \
    } while (0)

#define FENCE asm volatile("" ::: "memory")
#define BARRIER do { FENCE; __builtin_amdgcn_s_barrier(); FENCE; } while (0)
#define LGKM0  do { asm volatile("s_waitcnt lgkmcnt(0)" ::: "memory"); \
                    __builtin_amdgcn_sched_barrier(0); } while (0)

// one K-tile, 2 barrier-disciplined phases of 16 MFMA each.
// ENDW: 4 = steady-state counted wait; 0 = drain (tail); -1 = none (last).
#define TILE(bi, bnext, t2, ISSUE, ENDW) do {                                  \
        bf16x8 af[4], bfr[4];                                                  \
        /* ---- phase 0 pre: 8 ds_reads + A-stage issue ---- */                \
        _Pragma("unroll") for (int i = 0; i < 4; ++i)                          \
            af[i] = *(const bf16x8*)&As[bi][abase + i * 16 * BK];              \
        _Pragma("unroll") for (int j = 0; j < 4; ++j)                          \
            bfr[j] = *(const bf16x8*)&Bs[bi][bbase + j * 16 * BK];             \
        if (ISSUE) { STAGE_A(bnext, t2); }                                     \
        BARRIER;                                                               \
        LGKM0;                                                                 \
        __builtin_amdgcn_s_setprio(1);                                         \
        _Pragma("unroll") for (int i = 0; i < 4; ++i)                          \
        _Pragma("unroll") for (int j = 0; j < 4; ++j)                          \
            acc[0][i][j] = __builtin_amdgcn_mfma_f32_16x16x32_bf16(            \
                af[i], bfr[j], acc[0][i][j], 0, 0, 0);                         \
        __builtin_amdgcn_s_setprio(0);                                         \
        BARRIER;                                                               \
        __builtin_amdgcn_sched_barrier(0);                                     \
        /* ---- phase 1 pre: 4 ds_reads + B-stage issue ---- */                \
        _Pragma("unroll") for (int i = 0; i < 4; ++i)                          \
            af[i] = *(const bf16x8*)&As[bi][abase + (64 + i * 16) * BK];       \
        if (ISSUE) { STAGE_B(bnext, t2); }                                     \
        BARRIER;                                                               \
        LGKM0;                                                                 \
        __builtin_amdgcn_s_setprio(1);                                         \
        _Pragma("unroll") for (int i = 0; i < 4; ++i)                          \
        _Pragma("unroll") for (int j = 0; j < 4; ++j)                          \
            acc[1][i][j] = __builtin_amdgcn_mfma_f32_16x16x32_bf16(            \
                af[i], bfr[j], acc[1][i][j], 0, 0, 0);                         \
        __builtin_amdgcn_s_setprio(0);                                         \
        if ((ENDW) == 4) { asm volatile("s_waitcnt vmcnt(4)" ::: "memory"); }  \
        else if ((ENDW) == 0) { asm volatile("s_waitcnt vmcnt(0)" ::: "memory"); } \
        if ((ENDW) >= 0) { BARRIER; __builtin_amdgcn_sched_barrier(0); }       \
    } while (0)

    // prologue: stage tiles 0 and 1; vmcnt(4) leaves tile 1's 4 in flight.
    STAGE_A(0, 0); STAGE_B(0, 0);
    STAGE_A(1, 1); STAGE_B(1, 1);
    asm volatile("s_waitcnt vmcnt(4)" ::: "memory");
    __builtin_amdgcn_s_barrier();
    __builtin_amdgcn_sched_barrier(0);

    // main loop: tiles 0..125, unrolled x3 for compile-time buffer indices
    for (int it = 0; it < 42; ++it) {
        const int t0 = it * 3;
        TILE(0, 2, t0 + 2, true, 4);
        TILE(1, 0, t0 + 3, true, 4);
        TILE(2, 1, t0 + 4, true, 4);
    }
    // tile 126 (buf 0): nothing to stage; drain tile 127's loads.
    TILE(0, 2, 0, false, 0);
    // tile 127 (buf 1): last compute, no trailing wait/barrier.
    TILE(1, 0, 0, false, -1);

#undef TILE
#undef STAGE_A
#undef STAGE_B
#undef FENCE
#undef BARRIER
#undef LGKM0

    // C/D layout: col = lane&15, row = quad*4 + reg   [measured m89/m91]
#pragma unroll
    for (int mh = 0; mh < 2; ++mh)
#pragma unroll
        for (int j = 0; j < 4; ++j) {
            const int col = n0 + wn + j * 16 + lrow;
            const float bj = bias[col];
#pragma unroll
            for (int i = 0; i < 4; ++i) {
                const int rbase = m0 + wm + mh * 64 + i * 16 + quad * 4;
#pragma unroll
                for (int r = 0; r < 4; ++r)
                    C[(size_t)(rbase + r) * N_DIM + col] = acc[mh][i][j][r] + bj;
            }
        }
}

// ---------------------------------------------------------------- fallback (ws too small)
__global__ __launch_bounds__(256) void naive_gemm(const float* __restrict__ A,
                                                  const float* __restrict__ W,
                                                  const float* __restrict__ bias,
                                                  float* __restrict__ C) {
    const int col = blockIdx.x * 16 + threadIdx.x;
    const int row = blockIdx.y * 16 + threadIdx.y;
    float s = 0.f;
    for (int k = 0; k < K_DIM; ++k)
        s += A[(size_t)row * K_DIM + k] * W[(size_t)k * N_DIM + col];
    C[(size_t)row * N_DIM + col] = s + bias[col];
}

extern "C" void kernel_launch(void* const* d_in, const int* in_sizes, int n_in,
                              void* d_out, int out_size, void* d_ws, size_t ws_size,
                              hipStream_t stream) {
    const float* A = (const float*)d_in[0];
    const float* W = (const float*)d_in[1];
    const float* bias = (const float*)d_in[2];
    float* out = (float*)d_out;

    const size_t need = (size_t)2 * M_DIM * K_DIM * sizeof(unsigned short);  // 67 MB
    if (ws_size >= need) {
        unsigned short* Abf = (unsigned short*)d_ws;
        unsigned short* Wt = Abf + (size_t)M_DIM * K_DIM;
        prep_a<<<2048, 256, 0, stream>>>(A, Abf);
        prep_w<<<2048, 256, 0, stream>>>(W, Wt);
        gemm_bf16<<<(M_DIM / BM) * (N_DIM / BN), 512, 0, stream>>>(Abf, Wt, bias, out);
    } else {
        naive_gemm<<<dim3(N_DIM / 16, M_DIM / 16), dim3(16, 16), 0, stream>>>(A, W, bias, out);
    }
}

// Round 5
// 290.957 us; speedup vs baseline: 1.0058x; 1.0058x over previous
//
#include <hip/hip_runtime.h>
#include <stdint.h>

#define M_DIM 4096
#define N_DIM 4096
#define K_DIM 4096

#define BM 256
#define BN 256
#define BK 32

typedef __bf16 bf16x8 __attribute__((ext_vector_type(8)));
typedef float f32x4 __attribute__((ext_vector_type(4)));
typedef unsigned short us8 __attribute__((ext_vector_type(8)));
typedef unsigned short us4v __attribute__((ext_vector_type(4)));

// round-to-nearest-even fp32 -> bf16 bits
__device__ __forceinline__ unsigned short f2bf(float f) {
    unsigned u = __builtin_bit_cast(unsigned, f);
    u = (u + 0x7FFFu + ((u >> 16) & 1u)) >> 16;
    return (unsigned short)u;
}

// ---------------------------------------------------------------- prep (FUSED)
// One kernel = R1's prep_a body + R1's prep_w body concatenated (both proven
// correct at R2/R4). 2048 blocks x 256 thr. Fused so the prep dispatch is
// larger than any gemm dispatch and surfaces in the rocprof top-5 with its
// own counters (attribution for the ~160us non-gemm time).
__global__ __launch_bounds__(256) void prep(const float* __restrict__ A,
                                            unsigned short* __restrict__ Abf,
                                            const float* __restrict__ W,
                                            unsigned short* __restrict__ Wt) {
    const int t = threadIdx.x;

    // ---- part 1: A fp32 -> bf16 streaming convert (R1 prep_a body) ----
#pragma unroll
    for (int it = 0; it < 4; ++it) {
        const int i = blockIdx.x * 1024 + it * 256 + t;  // us8 index
        const float4 v0 = ((const float4*)A)[2 * i];
        const float4 v1 = ((const float4*)A)[2 * i + 1];
        us8 o;
        o[0] = f2bf(v0.x); o[1] = f2bf(v0.y); o[2] = f2bf(v0.z); o[3] = f2bf(v0.w);
        o[4] = f2bf(v1.x); o[5] = f2bf(v1.y); o[6] = f2bf(v1.z); o[7] = f2bf(v1.w);
        ((us8*)Abf)[i] = o;
    }

    // ---- part 2: W[k][n] fp32 -> Wt[n][k] bf16, 128k x 64n tile (R1 body) ----
    __shared__ __align__(16) unsigned short Lt[128 * 68];
    const int k0 = (blockIdx.x >> 6) * 128;
    const int n0 = (blockIdx.x & 63) * 64;

#pragma unroll
    for (int q = 0; q < 8; ++q) {
        const int idx = q * 256 + t;
        const int k = idx >> 4;      // 0..127
        const int a = idx & 15;      // float4 column granule (n-offset 4a)
        const float4 v = *(const float4*)(W + (size_t)(k0 + k) * N_DIM + n0 + 4 * a);
        const int ap = a ^ ((k ^ (k >> 3)) & 7);
        us4v o;
        o[0] = f2bf(v.x); o[1] = f2bf(v.y); o[2] = f2bf(v.z); o[3] = f2bf(v.w);
        *(us4v*)(Lt + k * 68 + 4 * ap) = o;
    }
    __syncthreads();

#pragma unroll
    for (int q = 0; q < 4; ++q) {
        const int s = q * 256 + t;
        const int n = s >> 4;        // 0..63
        const int c = s & 15;        // k-octet 0..15
        us8 o;
#pragma unroll
        for (int j = 0; j < 8; ++j) {
            const int k = 8 * c + j;
            const int ap = (n >> 2) ^ ((k ^ (k >> 3)) & 7);
            o[j] = Lt[k * 68 + 4 * ap + (n & 3)];
        }
        *(us8*)(Wt + (size_t)(n0 + n) * K_DIM + k0 + 8 * c) = o;
    }
}

// ---------------------------------------------------------------- GEMM
// REVERTED to the R2 schedule verbatim (125.0 us, MfmaUtil 45.5%, conflicts 0).
// R3/R4's 4-barrier phase split measured SLOWER (130.4 us) -> refuted.
// 256x256 tile, BK=32, 512 threads (8 waves, 2M x 4N), per-wave 128x64 out.
// Triple-buffered LDS (96 KB), counted vmcnt(4), raw s_barrier. Tile t issues
// tile t+2's 4 global_load_lds; vmcnt(4) at end of tile t forces t+1's loads
// landed while t+2's stay in flight. Tail: vmcnt(0) drain before tile 127.
__device__ __forceinline__ void load_lds16(const void* g, void* l) {
    __builtin_amdgcn_global_load_lds(
        (const __attribute__((address_space(1))) void*)g,
        (__attribute__((address_space(3))) void*)l,
        16, 0, 0);
}

__global__ __launch_bounds__(512, 2) void gemm_bf16(const unsigned short* __restrict__ A,
                                                    const unsigned short* __restrict__ Bt,
                                                    const float* __restrict__ bias,
                                                    float* __restrict__ C) {
    __shared__ __align__(16) unsigned short As[3][BM * BK];  // 3 x 16 KB
    __shared__ __align__(16) unsigned short Bs[3][BN * BK];  // 3 x 16 KB

    // XCD-aware swizzle: 256 blocks, 8 XCDs, 32 consecutive tiles per XCD
    const int bid = blockIdx.x;
    const int g = (bid & 7) * 32 + (bid >> 3);
    const int m0 = (g >> 4) * BM;
    const int n0 = (g & 15) * BN;

    const int tid = threadIdx.x;
    const int lane = tid & 63;
    const int wave = tid >> 6;            // 0..7
    const int wm = (wave >> 2) * 128;     // 2 M-halves of 128
    const int wn = (wave & 3) * 64;       // 4 N-quarters of 64
    const int lrow = lane & 15;
    const int quad = lane >> 4;
    const int kofs = (quad ^ ((lrow >> 1) & 3)) * 8;

    // staging: thread t fills 16B slots t and 512+t of each buffer.
    // slot s: row r = s>>2, phys chunk p = s&3 holds logical chunk
    // p ^ ((r>>1)&3); for both slots the xor term is (t>>3)&3.
    const int r0 = tid >> 2;                          // 0..127
    const int c0 = (tid & 3) ^ ((tid >> 3) & 3);
    const unsigned short* agp0 = A + (size_t)(m0 + r0) * K_DIM + c0 * 8;
    const unsigned short* agp1 = agp0 + (size_t)128 * K_DIM;
    const unsigned short* bgp0 = Bt + (size_t)(n0 + r0) * K_DIM + c0 * 8;
    const unsigned short* bgp1 = bgp0 + (size_t)128 * K_DIM;

    const int abase = (wm + lrow) * BK + kofs;
    const int bbase = (wn + lrow) * BK + kofs;

    f32x4 acc[2][4][4] = {};

#define STAGE_A(bi, t) do {                                   \
        load_lds16(agp0 + (size_t)(t) * BK, &As[bi][tid * 8]);        \
        load_lds16(agp1 + (size_t)(t) * BK, &As[bi][4096 + tid * 8]); \
    } while (0)
#define STAGE_B(bi, t) do {                                   \
        load_lds16(bgp0 + (size_t)(t) * BK, &Bs[bi][tid * 8]);        \
        load_lds16(bgp1 + (size_t)(t) * BK, &Bs[bi][4096 + tid * 8]); \
    } while (0)

// one K-tile: 2 phases of 16 MFMA (M-half 0 then 1); B frags reused across
// both phases. Staging of tile t+2 interleaved (A at phase0, B at phase1).
#define TILE(bi, bnext, t2, ISSUE) do {                                        \
        bf16x8 af[4], bfr[4];                                                  \
        _Pragma("unroll") for (int i = 0; i < 4; ++i)                          \
            af[i] = *(const bf16x8*)&As[bi][abase + i * 16 * BK];              \
        _Pragma("unroll") for (int j = 0; j < 4; ++j)                          \
            bfr[j] = *(const bf16x8*)&Bs[bi][bbase + j * 16 * BK];             \
        if (ISSUE) { STAGE_A(bnext, t2); }                                     \
        __builtin_amdgcn_s_setprio(1);                                         \
        _Pragma("unroll") for (int i = 0; i < 4; ++i)                          \
        _Pragma("unroll") for (int j = 0; j < 4; ++j)                          \
            acc[0][i][j] = __builtin_amdgcn_mfma_f32_16x16x32_bf16(            \
                af[i], bfr[j], acc[0][i][j], 0, 0, 0);                         \
        __builtin_amdgcn_s_setprio(0);                                         \
        _Pragma("unroll") for (int i = 0; i < 4; ++i)                          \
            af[i] = *(const bf16x8*)&As[bi][abase + (64 + i * 16) * BK];       \
        if (ISSUE) { STAGE_B(bnext, t2); }                                     \
        __builtin_amdgcn_s_setprio(1);                                         \
        _Pragma("unroll") for (int i = 0; i < 4; ++i)                          \
        _Pragma("unroll") for (int j = 0; j < 4; ++j)                          \
            acc[1][i][j] = __builtin_amdgcn_mfma_f32_16x16x32_bf16(            \
                af[i], bfr[j], acc[1][i][j], 0, 0, 0);                         \
        __builtin_amdgcn_s_setprio(0);                                         \
        __builtin_amdgcn_sched_barrier(0);                                     \
    } while (0)

#define TILE_END4                                              \
        asm volatile("s_waitcnt vmcnt(4)" ::: "memory");       \
        __builtin_amdgcn_s_barrier();                          \
        __builtin_amdgcn_sched_barrier(0);

    // prologue: stage tiles 0 and 1; require tile 0 landed (vmcnt(4) leaves
    // tile 1's 4 loads in flight), then barrier.
    STAGE_A(0, 0); STAGE_B(0, 0);
    STAGE_A(1, 1); STAGE_B(1, 1);
    asm volatile("s_waitcnt vmcnt(4)" ::: "memory");
    __builtin_amdgcn_s_barrier();
    __builtin_amdgcn_sched_barrier(0);

    // main loop: tiles 0..125, unrolled x3 for compile-time buffer indices
    for (int it = 0; it < 42; ++it) {
        const int t0 = it * 3;
        TILE(0, 2, t0 + 2, true); TILE_END4
        TILE(1, 0, t0 + 3, true); TILE_END4
        TILE(2, 1, t0 + 4, true); TILE_END4
    }
    // tile 126 (buf 0): nothing left to stage; must force tile 127's loads
    // (issued at t=125, only 4 outstanding) -> vmcnt(0), NOT vmcnt(4).
    TILE(0, 2, 0, false);
    asm volatile("s_waitcnt vmcnt(0)" ::: "memory");
    __builtin_amdgcn_s_barrier();
    __builtin_amdgcn_sched_barrier(0);
    // tile 127 (buf 1): last compute, no trailing barrier needed
    TILE(1, 0, 0, false);

#undef TILE
#undef TILE_END4
#undef STAGE_A
#undef STAGE_B

    // C/D layout: col = lane&15, row = quad*4 + reg   [measured m89/m91]
#pragma unroll
    for (int mh = 0; mh < 2; ++mh)
#pragma unroll
        for (int j = 0; j < 4; ++j) {
            const int col = n0 + wn + j * 16 + lrow;
            const float bj = bias[col];
#pragma unroll
            for (int i = 0; i < 4; ++i) {
                const int rbase = m0 + wm + mh * 64 + i * 16 + quad * 4;
#pragma unroll
                for (int r = 0; r < 4; ++r)
                    C[(size_t)(rbase + r) * N_DIM + col] = acc[mh][i][j][r] + bj;
            }
        }
}

// ---------------------------------------------------------------- fallback (ws too small)
__global__ __launch_bounds__(256) void naive_gemm(const float* __restrict__ A,
                                                  const float* __restrict__ W,
                                                  const float* __restrict__ bias,
                                                  float* __restrict__ C) {
    const int col = blockIdx.x * 16 + threadIdx.x;
    const int row = blockIdx.y * 16 + threadIdx.y;
    float s = 0.f;
    for (int k = 0; k < K_DIM; ++k)
        s += A[(size_t)row * K_DIM + k] * W[(size_t)k * N_DIM + col];
    C[(size_t)row * N_DIM + col] = s + bias[col];
}

extern "C" void kernel_launch(void* const* d_in, const int* in_sizes, int n_in,
                              void* d_out, int out_size, void* d_ws, size_t ws_size,
                              hipStream_t stream) {
    const float* A = (const float*)d_in[0];
    const float* W = (const float*)d_in[1];
    const float* bias = (const float*)d_in[2];
    float* out = (float*)d_out;

    const size_t need = (size_t)2 * M_DIM * K_DIM * sizeof(unsigned short);  // 67 MB
    if (ws_size >= need) {
        unsigned short* Abf = (unsigned short*)d_ws;
        unsigned short* Wt = Abf + (size_t)M_DIM * K_DIM;
        prep<<<2048, 256, 0, stream>>>(A, Abf, W, Wt);
        gemm_bf16<<<(M_DIM / BM) * (N_DIM / BN), 512, 0, stream>>>(Abf, Wt, bias, out);
    } else {
        naive_gemm<<<dim3(N_DIM / 16, M_DIM / 16), dim3(16, 16), 0, stream>>>(A, W, bias, out);
    }
}

// Round 7
// 288.658 us; speedup vs baseline: 1.0138x; 1.0080x over previous
//
#include <hip/hip_runtime.h>
#include <stdint.h>

#define M_DIM 4096
#define N_DIM 4096
#define K_DIM 4096

#define BM 256
#define BN 256
#define BK 64
#define NTILES (K_DIM / BK)   // 64 K-tiles

typedef __bf16 bf16x8 __attribute__((ext_vector_type(8)));
typedef float f32x4 __attribute__((ext_vector_type(4)));
typedef unsigned short us8 __attribute__((ext_vector_type(8)));
typedef unsigned short us4v __attribute__((ext_vector_type(4)));

// round-to-nearest-even fp32 -> bf16 bits
__device__ __forceinline__ unsigned short f2bf(float f) {
    unsigned u = __builtin_bit_cast(unsigned, f);
    u = (u + 0x7FFFu + ((u >> 16) & 1u)) >> 16;
    return (unsigned short)u;
}

// ---------------------------------------------------------------- prep (UNCHANGED)
__global__ __launch_bounds__(256) void prep(const float* __restrict__ A,
                                            unsigned short* __restrict__ Abf,
                                            const float* __restrict__ W,
                                            unsigned short* __restrict__ Wt) {
    const int t = threadIdx.x;

    // ---- part 1: A fp32 -> bf16 streaming convert ----
#pragma unroll
    for (int it = 0; it < 4; ++it) {
        const int i = blockIdx.x * 1024 + it * 256 + t;  // us8 index
        const float4 v0 = ((const float4*)A)[2 * i];
        const float4 v1 = ((const float4*)A)[2 * i + 1];
        us8 o;
        o[0] = f2bf(v0.x); o[1] = f2bf(v0.y); o[2] = f2bf(v0.z); o[3] = f2bf(v0.w);
        o[4] = f2bf(v1.x); o[5] = f2bf(v1.y); o[6] = f2bf(v1.z); o[7] = f2bf(v1.w);
        ((us8*)Abf)[i] = o;
    }

    // ---- part 2: W[k][n] fp32 -> Wt[n][k] bf16, 128k x 64n tile ----
    __shared__ __align__(16) unsigned short Lt[128 * 68];
    const int k0 = (blockIdx.x >> 6) * 128;
    const int n0 = (blockIdx.x & 63) * 64;

#pragma unroll
    for (int q = 0; q < 8; ++q) {
        const int idx = q * 256 + t;
        const int k = idx >> 4;
        const int a = idx & 15;
        const float4 v = *(const float4*)(W + (size_t)(k0 + k) * N_DIM + n0 + 4 * a);
        const int ap = a ^ ((k ^ (k >> 3)) & 7);
        us4v o;
        o[0] = f2bf(v.x); o[1] = f2bf(v.y); o[2] = f2bf(v.z); o[3] = f2bf(v.w);
        *(us4v*)(Lt + k * 68 + 4 * ap) = o;
    }
    __syncthreads();

#pragma unroll
    for (int q = 0; q < 4; ++q) {
        const int s = q * 256 + t;
        const int n = s >> 4;
        const int c = s & 15;
        us8 o;
#pragma unroll
        for (int j = 0; j < 8; ++j) {
            const int k = 8 * c + j;
            const int ap = (n >> 2) ^ ((k ^ (k >> 3)) & 7);
            o[j] = Lt[k * 68 + 4 * ap + (n & 3)];
        }
        *(us8*)(Wt + (size_t)(n0 + n) * K_DIM + k0 + 8 * c) = o;
    }
}

// ---------------------------------------------------------------- GEMM (R7 = R6 + kk-XOR fix)
// 256x256 tile, BK=64, 512 threads (8 waves, 2M x 4N), per-wave 128x64 out.
// 2 LDS buffers (2 x 64 KB). ONE barrier + ONE vmcnt(0) per K-tile; tile t+1's
// 8 global_load_lds issued at START of tile t (full-tile cover before drain).
// Ledger: reads of buf b retire before each wave's lgkmcnt(0) -> before the
// tile-end barrier -> staging buf b next tile cannot race; vmcnt(0)+barrier
// before the swap guarantees staged data landed.
// Swizzle: phys octet p of row r holds LOGICAL k-octet p^(r&7) (pre-swizzled
// global source). Fragment read of logical octet l at row r is at phys
// l^(r&7); for l = kk*4+quad and r&7 = lrow&7 this is p0 ^ (kk<<2) where
// p0 = quad^(lrow&7).  *** R6 BUG: used p0 + 4*kk (ADD) -> for lrow&7>=4
// wrapped into the next row; fixed via abase^32 (XOR flips only p0's bit2).
__device__ __forceinline__ void load_lds16(const void* g, void* l) {
    __builtin_amdgcn_global_load_lds(
        (const __attribute__((address_space(1))) void*)g,
        (__attribute__((address_space(3))) void*)l,
        16, 0, 0);
}

__global__ __launch_bounds__(512, 2) void gemm_bf16(const unsigned short* __restrict__ A,
                                                    const unsigned short* __restrict__ Bt,
                                                    const float* __restrict__ bias,
                                                    float* __restrict__ C) {
    __shared__ __align__(16) unsigned short As[2][16384];  // [buf][q*4096 + slot]
    __shared__ __align__(16) unsigned short Bs[2][16384];

    // XCD-aware swizzle: 256 blocks, 8 XCDs, 32 consecutive tiles per XCD
    const int bid = blockIdx.x;
    const int g = (bid & 7) * 32 + (bid >> 3);
    const int m0 = (g >> 4) * BM;
    const int n0 = (g & 15) * BN;

    const int tid = threadIdx.x;
    const int lane = tid & 63;
    const int wave = tid >> 6;            // 0..7
    const int lrow = lane & 15;
    const int quad = lane >> 4;

    // staging addresses: thread t -> row (t>>3) of each 64-row q-block,
    // phys chunk (t&7) holds logical k-octet sl = (t&7)^((t>>3)&7).
    const int sr = tid >> 3;              // 0..63
    const int sl = (tid & 7) ^ (sr & 7);  // logical k-octet
    const unsigned short* ag[4];
    const unsigned short* bg[4];
#pragma unroll
    for (int q = 0; q < 4; ++q) {
        ag[q] = A  + (size_t)(m0 + q * 64 + sr) * K_DIM + sl * 8;
        bg[q] = Bt + (size_t)(n0 + q * 64 + sr) * K_DIM + sl * 8;
    }

    // fragment-read constants
    const int p0 = quad ^ (lrow & 7);     // phys octet for kk=0; kk=1 is p0^4
    const int aq0 = (wave >> 2) * 2;      // A q-block base (+mh)
    const int bq  = wave & 3;             // B q-block (wave's 64-col quarter)
    const int abase0 = aq0 * 4096 + lrow * 64 + p0 * 8;
    const int bbase0 = bq * 4096 + lrow * 64 + p0 * 8;
    // kk=1 base: XOR 32 shorts flips exactly bit2 of the phys-octet field
    // (p0*8 in {0..56}; lrow*64 and q-block offsets occupy higher bits).
    const int abase[2] = {abase0, abase0 ^ 32};
    const int bbase[2] = {bbase0, bbase0 ^ 32};

    f32x4 acc[2][4][4] = {};

#define STAGE(bi, t) do {                                                      \
        _Pragma("unroll") for (int q = 0; q < 4; ++q) {                        \
            load_lds16(ag[q] + (size_t)(t) * BK, &As[bi][q * 4096 + tid * 8]); \
            load_lds16(bg[q] + (size_t)(t) * BK, &Bs[bi][q * 4096 + tid * 8]); \
        }                                                                      \
    } while (0)

#define LGKM0 do { asm volatile("s_waitcnt lgkmcnt(0)" ::: "memory");          \
                   __builtin_amdgcn_sched_barrier(0); } while (0)

// one K-tile (K=64): stage tile t2 into buf bnext at START (max cover), then
// two mh-halves of {ds_read frags; lgkm0; 32 MFMA}.
#define TILE(bi, bnext, t2, ISSUE, ENDW) do {                                  \
        if (ISSUE) { STAGE(bnext, t2); }                                       \
        bf16x8 af[4][2], bfr[4][2];                                            \
        _Pragma("unroll") for (int j = 0; j < 4; ++j)                          \
        _Pragma("unroll") for (int kk = 0; kk < 2; ++kk)                       \
            bfr[j][kk] = *(const bf16x8*)&Bs[bi][bbase[kk] + j * 1024];        \
        _Pragma("unroll") for (int i = 0; i < 4; ++i)                          \
        _Pragma("unroll") for (int kk = 0; kk < 2; ++kk)                       \
            af[i][kk] = *(const bf16x8*)&As[bi][abase[kk] + i * 1024];         \
        LGKM0;                                                                 \
        __builtin_amdgcn_s_setprio(1);                                         \
        _Pragma("unroll") for (int i = 0; i < 4; ++i)                          \
        _Pragma("unroll") for (int j = 0; j < 4; ++j)                          \
        _Pragma("unroll") for (int kk = 0; kk < 2; ++kk)                       \
            acc[0][i][j] = __builtin_amdgcn_mfma_f32_16x16x32_bf16(            \
                af[i][kk], bfr[j][kk], acc[0][i][j], 0, 0, 0);                 \
        __builtin_amdgcn_s_setprio(0);                                         \
        _Pragma("unroll") for (int i = 0; i < 4; ++i)                          \
        _Pragma("unroll") for (int kk = 0; kk < 2; ++kk)                       \
            af[i][kk] = *(const bf16x8*)&As[bi][abase[kk] + 4096 + i * 1024];  \
        LGKM0;                                                                 \
        __builtin_amdgcn_s_setprio(1);                                         \
        _Pragma("unroll") for (int i = 0; i < 4; ++i)                          \
        _Pragma("unroll") for (int j = 0; j < 4; ++j)                          \
        _Pragma("unroll") for (int kk = 0; kk < 2; ++kk)                       \
            acc[1][i][j] = __builtin_amdgcn_mfma_f32_16x16x32_bf16(            \
                af[i][kk], bfr[j][kk], acc[1][i][j], 0, 0, 0);                 \
        __builtin_amdgcn_s_setprio(0);                                         \
        if (ENDW) {                                                            \
            asm volatile("s_waitcnt vmcnt(0)" ::: "memory");                   \
            __builtin_amdgcn_s_barrier();                                      \
            __builtin_amdgcn_sched_barrier(0);                                 \
        }                                                                      \
    } while (0)

    // prologue: stage tile 0, drain, barrier.
    STAGE(0, 0);
    asm volatile("s_waitcnt vmcnt(0)" ::: "memory");
    __builtin_amdgcn_s_barrier();
    __builtin_amdgcn_sched_barrier(0);

    // main: tiles 0..61 (x2 unroll for buffer parity), staging t+1 each tile
    for (int it = 0; it < 31; ++it) {
        const int t0 = 2 * it;
        TILE(0, 1, t0 + 1, true, 1);
        TILE(1, 0, t0 + 2, true, 1);
    }
    // tile 62: stage 63; tile 63: last, no stage / no trailing barrier
    TILE(0, 1, 63, true, 1);
    TILE(1, 0, 0, false, 0);

#undef TILE
#undef STAGE
#undef LGKM0

    // C/D layout: col = lane&15, row = quad*4 + reg   [measured m89/m91]
    const int wm = (wave >> 2) * 128;
    const int wn = (wave & 3) * 64;
#pragma unroll
    for (int mh = 0; mh < 2; ++mh)
#pragma unroll
        for (int j = 0; j < 4; ++j) {
            const int col = n0 + wn + j * 16 + lrow;
            const float bj = bias[col];
#pragma unroll
            for (int i = 0; i < 4; ++i) {
                const int rbase = m0 + wm + mh * 64 + i * 16 + quad * 4;
#pragma unroll
                for (int r = 0; r < 4; ++r)
                    C[(size_t)(rbase + r) * N_DIM + col] = acc[mh][i][j][r] + bj;
            }
        }
}

// ---------------------------------------------------------------- fallback (ws too small)
__global__ __launch_bounds__(256) void naive_gemm(const float* __restrict__ A,
                                                  const float* __restrict__ W,
                                                  const float* __restrict__ bias,
                                                  float* __restrict__ C) {
    const int col = blockIdx.x * 16 + threadIdx.x;
    const int row = blockIdx.y * 16 + threadIdx.y;
    float s = 0.f;
    for (int k = 0; k < K_DIM; ++k)
        s += A[(size_t)row * K_DIM + k] * W[(size_t)k * N_DIM + col];
    C[(size_t)row * N_DIM + col] = s + bias[col];
}

extern "C" void kernel_launch(void* const* d_in, const int* in_sizes, int n_in,
                              void* d_out, int out_size, void* d_ws, size_t ws_size,
                              hipStream_t stream) {
    const float* A = (const float*)d_in[0];
    const float* W = (const float*)d_in[1];
    const float* bias = (const float*)d_in[2];
    float* out = (float*)d_out;

    const size_t need = (size_t)2 * M_DIM * K_DIM * sizeof(unsigned short);  // 67 MB
    if (ws_size >= need) {
        unsigned short* Abf = (unsigned short*)d_ws;
        unsigned short* Wt = Abf + (size_t)M_DIM * K_DIM;
        prep<<<2048, 256, 0, stream>>>(A, Abf, W, Wt);
        gemm_bf16<<<(M_DIM / BM) * (N_DIM / BN), 512, 0, stream>>>(Abf, Wt, bias, out);
    } else {
        naive_gemm<<<dim3(N_DIM / 16, M_DIM / 16), dim3(16, 16), 0, stream>>>(A, W, bias, out);
    }
}